// Round 17
// baseline (32.283 us; speedup 1.0000x reference)
//
#include <hip/hip_runtime.h>

// B=1024, A=256, E=4, M1=128, M2=16, H1=32, H2=64
#define XROW 1537
#define NTHR 256
#define SP   320              // padded slot space: 5 strips-of-64 (max St4 = 268)

// ws layout (floats): [0,128) Tsort[4][32]; [128,128+16896) AC[e][33][64][2]
// h2_pre[o] = v*A_k[o] + C_k[o] on interval k — exact piecewise-affine
// collapse of relu(v*W1+b1) @ W2 + b2 in the scalar v.

__device__ __forceinline__ float rlf(float x, int u) {
    return __uint_as_float(__builtin_amdgcn_readlane(__float_as_uint(x), u));
}
__device__ __forceinline__ int rli(int x, int u) {
    return __builtin_amdgcn_readlane(x, u);
}

// prep v3: grid = 132 (= 4 experts x 33 intervals), 64 threads (lane = o).
__global__ void __launch_bounds__(64)
be_prep(const float* __restrict__ W1, const float* __restrict__ b1,
        const float* __restrict__ W2, const float* __restrict__ b2,
        float* __restrict__ ws)
{
    const int e    = blockIdx.x / 33;
    const int k    = blockIdx.x % 33;
    const int lane = threadIdx.x;

    float w1v_l = 0.f, b1v_l = 0.f, ti = 3.4e38f;
    if (lane < 32) {
        w1v_l = W1[e * 32 + lane];
        b1v_l = b1[e * 32 + lane];
        ti = (w1v_l != 0.f) ? (-b1v_l / w1v_l) : 3.4e38f;
    }
    int rank = 0;
    #pragma unroll
    for (int j = 0; j < 32; ++j) {
        float tj = rlf(ti, j);
        rank += (tj < ti) || (tj == ti && j < lane);
    }
    if (k == 0 && lane < 32) ws[e * 32 + rank] = ti;  // sorted thresholds

    const int o = lane;
    float A = 0.f, C = b2[e * 64 + o];
    #pragma unroll
    for (int i = 0; i < 32; ++i) {
        float w1v = rlf(w1v_l, i);
        float b1v = rlf(b1v_l, i);
        int   r   = rli(rank, i);
        float w2v = W2[(e * 32 + i) * 64 + o];
        bool act = (w1v > 0.f) ? (k > r)
                 : ((w1v < 0.f) ? (k <= r) : (b1v > 0.f));
        float m = act ? 1.f : 0.f;
        A = fmaf(w1v * m, w2v, A);
        C = fmaf(b1v * m, w2v, C);
    }
    float* AC = ws + 128;
    float2 p; p.x = A; p.y = C;
    *(float2*)&AC[(e * 33 + k) * 128 + 2 * o] = p;
}

__global__ void __launch_bounds__(NTHR)
be_kernel(const float* __restrict__ x,
          const float* __restrict__ W3, const float* __restrict__ b3,
          const float* __restrict__ wsr,
          float* __restrict__ out)
{
    __shared__ int2   kv[SP];                     // {kea, bits(va)}, pads = 0
    __shared__ __align__(16) float4 Rm4[SP];      // [slot] -> R[0..3], masked
    __shared__ float Ts_l[128];                   // sorted thresholds
    // UNION: Spart (S-phase, 16 KB) overlays Pp (8 KB) + Pr5 (2.56 KB);
    // lifetimes separated by the __syncthreads after the Sred reduce.
    __shared__ __align__(16) char uni[16384];
    __shared__ __align__(16) float Sred[4][64][4];      // [e][i][c]
    __shared__ float Tpart[4][4][16];
    __shared__ float T16[16];
    __shared__ int   cntw[4][4];

    float (*Spart)[4][64][4] = (float (*)[4][64][4])uni;  // [w][e][o][c]
    float (*Pp)[128][4]      = (float (*)[128][4])uni;    // [w=ee][m][c]
    float *Pr5               = (float*)(uni + 8192);      // 128*5 floats

    const int tid  = threadIdx.x;
    const int b    = blockIdx.x;
    const int lane = tid & 63;
    const int w    = tid >> 6;
    const long xb  = (long)b * XROW;
    const float* ACg = wsr + 128;

    // ---- per-a input (a = tid); scalar loads (xb odd-strided, unaligned) ----
    float v = x[xb + 2 * tid];
    int e = (int)x[xb + 2 * tid + 1];
    e = max(0, min(3, e));
    int N = (int)x[xb + 1536];
    float maskf = (tid < N) ? 1.f : 0.f;
    if (tid < 128) Ts_l[tid] = wsr[tid];

    // ---- ballot compaction (deterministic ranks) ----
    unsigned long long mybal = 0ull;
    #pragma unroll
    for (int q = 0; q < 4; ++q) {
        unsigned long long bq = __ballot(e == q);
        if (lane == 0) cntw[w][q] = __popcll(bq);
        if (e == q) mybal = bq;
    }
    int rank = __popcll(mybal & ((1ull << lane) - 1ull));

    // zero padded tables
    for (int idx = tid; idx < SP; idx += NTHR) {
        kv[idx] = make_int2(0, 0);
        Rm4[idx] = make_float4(0.f, 0.f, 0.f, 0.f);
    }
    __syncthreads();           // Ts_l + zeros + cntw visible

    int c0 = cntw[0][0] + cntw[1][0] + cntw[2][0] + cntw[3][0];
    int c1 = cntw[0][1] + cntw[1][1] + cntw[2][1] + cntw[3][1];
    int c2_ = cntw[0][2] + cntw[1][2] + cntw[2][2] + cntw[3][2];
    int c3 = cntw[0][3] + cntw[1][3] + cntw[2][3] + cntw[3][3];
    const int B0 = 0;
    const int B1 = (B0 + c0 + 3) & ~3;
    const int B2 = (B1 + c1 + 3) & ~3;
    const int B3 = (B2 + c2_ + 3) & ~3;
    const int St4 = (B3 + c3 + 3) & ~3;             // <= 268 <= SP

    {
        int offw = 0;
        #pragma unroll
        for (int w2 = 0; w2 < 4; ++w2) if (w2 < w) offw += cntw[w2][e];
        int Bsel = (e == 0) ? B0 : ((e == 1) ? B1 : ((e == 2) ? B2 : B3));
        int ci = Bsel + offw + rank;
        // interval index for own (e, v) — folded into scatter
        const float* Ts = &Ts_l[e * 32];
        int k = 0;
        #pragma unroll
        for (int st = 32; st >= 1; st >>= 1)
            if (k + st <= 32 && Ts[k + st - 1] <= v) k += st;
        kv[ci] = make_int2((e * 33 + k) * 128, __float_as_int(v));
        float4 r4;
        r4.x = x[xb + 512 + 4 * tid + 0] * maskf;
        r4.y = x[xb + 512 + 4 * tid + 1] * maskf;
        r4.z = x[xb + 512 + 4 * tid + 2] * maskf;
        r4.w = x[xb + 512 + 4 * tid + 3] * maskf;
        Rm4[ci] = r4;
    }
    __syncthreads();

    // ---- T[e][c] = sum_a R_masked; fixed-trip masked loop (pads = 0) ----
    {
        int te = tid >> 6, tc = (tid >> 4) & 3, tk = tid & 15;
        int s0 = (te == 0) ? B0 : ((te == 1) ? B1 : ((te == 2) ? B2 : B3));
        int s1 = (te == 0) ? B1 : ((te == 1) ? B2 : ((te == 2) ? B3 : St4));
        float ts = 0.f;
        #pragma unroll
        for (int j = 0; j < 20; ++j) {
            int s = j * 16 + tk;
            float val = ((const float*)&Rm4[s])[tc];
            ts += (s >= s0 && s < s1) ? val : 0.f;
        }
        Tpart[te][tc][tk] = ts;
    }
    __syncthreads();
    if (tid < 16) {
        float t = 0.f;
        #pragma unroll
        for (int k = 0; k < 16; ++k) t += Tpart[tid >> 2][tid & 3][k];
        T16[tid] = t;         // consumed in P phase (after Spart barrier)
    }

    // ---- barrier-free S accumulation: wave w owns strips {t*64 + w*16} ----
    float Se[4][4];           // [expert][c] accumulators, static indexed
    #pragma unroll
    for (int i = 0; i < 4; ++i)
        #pragma unroll
        for (int j = 0; j < 4; ++j) Se[i][j] = 0.f;

    #pragma unroll
    for (int t = 0; t < 5; ++t) {
        const int base = t * 64 + w * 16;
        if (base >= St4) continue;           // wave-uniform: all-pad strip
        int2   kvu = kv[base + (lane & 15)];     // lanes replicate 16 slots
        float4 r4u = Rm4[base + (lane & 15)];

        float2 ac16[16];
        #pragma unroll
        for (int u = 0; u < 16; ++u) {
            int s_k = rli(kvu.x, u);             // SGPR: coalesced saddr load
            ac16[u] = *(const float2*)&ACg[s_k + 2 * lane];
        }
        #pragma unroll
        for (int g = 0; g < 4; ++g) {            // 4-aligned, expert-pure groups
            float t0 = 0.f, t1 = 0.f, t2 = 0.f, t3 = 0.f;
            #pragma unroll
            for (int u4 = 0; u4 < 4; ++u4) {
                const int u = g * 4 + u4;
                float s_v = rlf(__int_as_float(kvu.y), u);
                float h = fmaxf(fmaf(s_v, ac16[u].x, ac16[u].y), 0.f);
                t0 = fmaf(h, rlf(r4u.x, u), t0);
                t1 = fmaf(h, rlf(r4u.y, u), t1);
                t2 = fmaf(h, rlf(r4u.z, u), t2);
                t3 = fmaf(h, rlf(r4u.w, u), t3);
            }
            const int gb = base + g * 4;
            int eg = (gb >= B1) + (gb >= B2) + (gb >= B3);
            eg = __builtin_amdgcn_readfirstlane(eg);   // wave-uniform branch
            if (eg == 0) {
                Se[0][0] += t0; Se[0][1] += t1; Se[0][2] += t2; Se[0][3] += t3;
            } else if (eg == 1) {
                Se[1][0] += t0; Se[1][1] += t1; Se[1][2] += t2; Se[1][3] += t3;
            } else if (eg == 2) {
                Se[2][0] += t0; Se[2][1] += t1; Se[2][2] += t2; Se[2][3] += t3;
            } else {
                Se[3][0] += t0; Se[3][1] += t1; Se[3][2] += t2; Se[3][3] += t3;
            }
        }
    }
    #pragma unroll
    for (int ee = 0; ee < 4; ++ee) {
        float4 s4; s4.x = Se[ee][0]; s4.y = Se[ee][1];
                   s4.z = Se[ee][2]; s4.w = Se[ee][3];
        *(float4*)&Spart[w][ee][lane][0] = s4;
    }
    __syncthreads();

    // ---- reduce Spart over waves: thread (e,i) ----
    {
        const int e_ = tid >> 6, i_ = tid & 63;
        float4 s0 = *(const float4*)&Spart[0][e_][i_][0];
        float4 s1 = *(const float4*)&Spart[1][e_][i_][0];
        float4 s2 = *(const float4*)&Spart[2][e_][i_][0];
        float4 s3 = *(const float4*)&Spart[3][e_][i_][0];
        float4 r; r.x = (s0.x + s1.x) + (s2.x + s3.x);
                  r.y = (s0.y + s1.y) + (s2.y + s3.y);
                  r.z = (s0.z + s1.z) + (s2.z + s3.z);
                  r.w = (s0.w + s1.w) + (s2.w + s3.w);
        *(float4*)&Sred[e_][i_][0] = r;
    }
    __syncthreads();   // Spart dead past here -> Pp/Pr5 reuse the bytes

    // ---- P partials: wave w = expert; lane m-pair {2*lane, 2*lane+1};
    //      W3/b3 read as float2 (8B-aligned) — half the VMEM instructions ----
    {
        float a0 = 0.f, a1 = 0.f, a2 = 0.f, a3 = 0.f;   // m = 2*lane
        float b0 = 0.f, b1_ = 0.f, b2_ = 0.f, b3_ = 0.f; // m = 2*lane+1
        const float* W3e = W3 + w * 8192;
        #pragma unroll 8
        for (int i = 0; i < 64; ++i) {
            const float4 s4 = *(const float4*)&Sred[w][i][0];  // broadcast
            const float2 wab = *(const float2*)&W3e[i * 128 + 2 * lane];
            a0 = fmaf(wab.x, s4.x, a0); a1 = fmaf(wab.x, s4.y, a1);
            a2 = fmaf(wab.x, s4.z, a2); a3 = fmaf(wab.x, s4.w, a3);
            b0 = fmaf(wab.y, s4.x, b0); b1_ = fmaf(wab.y, s4.y, b1_);
            b2_ = fmaf(wab.y, s4.z, b2_); b3_ = fmaf(wab.y, s4.w, b3_);
        }
        const float4 t4 = *(const float4*)&T16[w * 4];
        const float2 byab = *(const float2*)&b3[w * 128 + 2 * lane];
        a0 = fmaf(byab.x, t4.x, a0); a1 = fmaf(byab.x, t4.y, a1);
        a2 = fmaf(byab.x, t4.z, a2); a3 = fmaf(byab.x, t4.w, a3);
        b0 = fmaf(byab.y, t4.x, b0); b1_ = fmaf(byab.y, t4.y, b1_);
        b2_ = fmaf(byab.y, t4.z, b2_); b3_ = fmaf(byab.y, t4.w, b3_);
        float4 pa; pa.x = a0; pa.y = a1; pa.z = a2; pa.w = a3;
        float4 pb; pb.x = b0; pb.y = b1_; pb.z = b2_; pb.w = b3_;
        *(float4*)&Pp[w][2 * lane][0]     = pa;
        *(float4*)&Pp[w][2 * lane + 1][0] = pb;
    }
    __syncthreads();

    // ---- reduce Pp over experts -> Pr5 (disjoint region within uni) ----
    {
        const int m = tid >> 1, cp = tid & 1;
        float2 p0 = *(const float2*)&Pp[0][m][2 * cp];
        float2 p1 = *(const float2*)&Pp[1][m][2 * cp];
        float2 p2 = *(const float2*)&Pp[2][m][2 * cp];
        float2 p3 = *(const float2*)&Pp[3][m][2 * cp];
        Pr5[m * 5 + 2 * cp]     = (p0.x + p1.x) + (p2.x + p3.x);
        Pr5[m * 5 + 2 * cp + 1] = (p0.y + p1.y) + (p2.y + p3.y);
    }
    __syncthreads();

    // ---- D[m][n] = sum_c P[m][c] P[n][c]; 8 consecutive outputs/thread ----
    {
        const int m   = tid >> 1;
        const int nb8 = (tid & 1) << 3;
        float pm0 = Pr5[m * 5 + 0], pm1 = Pr5[m * 5 + 1];
        float pm2 = Pr5[m * 5 + 2], pm3 = Pr5[m * 5 + 3];
        float o8[8];
        #pragma unroll
        for (int r = 0; r < 8; ++r) {
            int n = nb8 + r;
            float d = pm0 * Pr5[n * 5 + 0];
            d = fmaf(pm1, Pr5[n * 5 + 1], d);
            d = fmaf(pm2, Pr5[n * 5 + 2], d);
            d = fmaf(pm3, Pr5[n * 5 + 3], d);
            o8[r] = d;
        }
        float* outb = out + (long)b * 2048 + tid * 8;
        float4 s0; s0.x = o8[0]; s0.y = o8[1]; s0.z = o8[2]; s0.w = o8[3];
        float4 s1; s1.x = o8[4]; s1.y = o8[5]; s1.z = o8[6]; s1.w = o8[7];
        *(float4*)&outb[0] = s0;
        *(float4*)&outb[4] = s1;
    }
}

extern "C" void kernel_launch(void* const* d_in, const int* in_sizes, int n_in,
                              void* d_out, int out_size, void* d_ws, size_t ws_size,
                              hipStream_t stream)
{
    const float* x  = (const float*)d_in[0];
    const float* W1 = (const float*)d_in[1];
    const float* b1 = (const float*)d_in[2];
    const float* W2 = (const float*)d_in[3];
    const float* b2 = (const float*)d_in[4];
    const float* W3 = (const float*)d_in[5];
    const float* b3 = (const float*)d_in[6];
    float* out = (float*)d_out;
    float* ws  = (float*)d_ws;       // needs 68096 bytes

    be_prep<<<132, 64, 0, stream>>>(W1, b1, W2, b2, ws);
    be_kernel<<<1024, NTHR, 0, stream>>>(x, W3, b3, ws, out);
}

// Round 18
// 30.205 us; speedup vs baseline: 1.0688x; 1.0688x over previous
//
#include <hip/hip_runtime.h>

// B=1024, A=256, E=4, M1=128, M2=16, H1=32, H2=64
#define XROW 1537
#define NTHR 256
#define SP   320              // padded slot space: 5 strips-of-64 (max St4 = 268)

// ws layout (floats): [0,128) Tsort[4][32]; [128,128+16896) AC[e][33][64][2]
// h2_pre[o] = v*A_k[o] + C_k[o] on interval k — exact piecewise-affine
// collapse of relu(v*W1+b1) @ W2 + b2 in the scalar v.

__device__ __forceinline__ float rlf(float x, int u) {
    return __uint_as_float(__builtin_amdgcn_readlane(__float_as_uint(x), u));
}
__device__ __forceinline__ int rli(int x, int u) {
    return __builtin_amdgcn_readlane(x, u);
}

// prep v3: grid = 132 (= 4 experts x 33 intervals), 64 threads (lane = o).
__global__ void __launch_bounds__(64)
be_prep(const float* __restrict__ W1, const float* __restrict__ b1,
        const float* __restrict__ W2, const float* __restrict__ b2,
        float* __restrict__ ws)
{
    const int e    = blockIdx.x / 33;
    const int k    = blockIdx.x % 33;
    const int lane = threadIdx.x;

    float w1v_l = 0.f, b1v_l = 0.f, ti = 3.4e38f;
    if (lane < 32) {
        w1v_l = W1[e * 32 + lane];
        b1v_l = b1[e * 32 + lane];
        ti = (w1v_l != 0.f) ? (-b1v_l / w1v_l) : 3.4e38f;
    }
    int rank = 0;
    #pragma unroll
    for (int j = 0; j < 32; ++j) {
        float tj = rlf(ti, j);
        rank += (tj < ti) || (tj == ti && j < lane);
    }
    if (k == 0 && lane < 32) ws[e * 32 + rank] = ti;  // sorted thresholds

    const int o = lane;
    float A = 0.f, C = b2[e * 64 + o];
    #pragma unroll
    for (int i = 0; i < 32; ++i) {
        float w1v = rlf(w1v_l, i);
        float b1v = rlf(b1v_l, i);
        int   r   = rli(rank, i);
        float w2v = W2[(e * 32 + i) * 64 + o];
        bool act = (w1v > 0.f) ? (k > r)
                 : ((w1v < 0.f) ? (k <= r) : (b1v > 0.f));
        float m = act ? 1.f : 0.f;
        A = fmaf(w1v * m, w2v, A);
        C = fmaf(b1v * m, w2v, C);
    }
    float* AC = ws + 128;
    float2 p; p.x = A; p.y = C;
    *(float2*)&AC[(e * 33 + k) * 128 + 2 * o] = p;
}

__global__ void __launch_bounds__(NTHR)
be_kernel(const float* __restrict__ x,
          const float* __restrict__ W3, const float* __restrict__ b3,
          const float* __restrict__ wsr,
          float* __restrict__ out)
{
    __shared__ int2   kv[SP];                     // {kea, bits(va)}, pads = 0
    __shared__ __align__(16) float4 Rm4[SP];      // [slot] -> R[0..3], masked
    __shared__ float Ts_l[128];                   // sorted thresholds
    // UNION: Spart (S-phase, 16 KB) overlays Pp (8 KB) + Pr5 (2.56 KB);
    // lifetimes separated by the __syncthreads after the Sred reduce.
    __shared__ __align__(16) char uni[16384];
    __shared__ __align__(16) float Sred[4][64][4];      // [e][i][c]
    __shared__ float Tpart[4][4][16];
    __shared__ float T16[16];
    __shared__ int   cntw[4][4];

    float (*Spart)[4][64][4] = (float (*)[4][64][4])uni;  // [w][e][o][c]
    float (*Pp)[128][4]      = (float (*)[128][4])uni;    // [w=ee][m][c]
    float *Pr5               = (float*)(uni + 8192);      // 128*5 floats

    const int tid  = threadIdx.x;
    const int b    = blockIdx.x;
    const int lane = tid & 63;
    const int w    = tid >> 6;
    const long xb  = (long)b * XROW;
    const float* ACg = wsr + 128;

    // ---- per-a input (a = tid); scalar loads (xb odd-strided, unaligned) ----
    float v = x[xb + 2 * tid];
    int e = (int)x[xb + 2 * tid + 1];
    e = max(0, min(3, e));
    int N = (int)x[xb + 1536];
    float maskf = (tid < N) ? 1.f : 0.f;
    if (tid < 128) Ts_l[tid] = wsr[tid];

    // ---- ballot compaction (deterministic ranks) ----
    unsigned long long mybal = 0ull;
    #pragma unroll
    for (int q = 0; q < 4; ++q) {
        unsigned long long bq = __ballot(e == q);
        if (lane == 0) cntw[w][q] = __popcll(bq);
        if (e == q) mybal = bq;
    }
    int rank = __popcll(mybal & ((1ull << lane) - 1ull));

    // zero padded tables
    for (int idx = tid; idx < SP; idx += NTHR) {
        kv[idx] = make_int2(0, 0);
        Rm4[idx] = make_float4(0.f, 0.f, 0.f, 0.f);
    }
    __syncthreads();           // Ts_l + zeros + cntw visible

    int c0 = cntw[0][0] + cntw[1][0] + cntw[2][0] + cntw[3][0];
    int c1 = cntw[0][1] + cntw[1][1] + cntw[2][1] + cntw[3][1];
    int c2_ = cntw[0][2] + cntw[1][2] + cntw[2][2] + cntw[3][2];
    int c3 = cntw[0][3] + cntw[1][3] + cntw[2][3] + cntw[3][3];
    const int B0 = 0;
    const int B1 = (B0 + c0 + 3) & ~3;
    const int B2 = (B1 + c1 + 3) & ~3;
    const int B3 = (B2 + c2_ + 3) & ~3;
    const int St4 = (B3 + c3 + 3) & ~3;             // <= 268 <= SP

    {
        int offw = 0;
        #pragma unroll
        for (int w2 = 0; w2 < 4; ++w2) if (w2 < w) offw += cntw[w2][e];
        int Bsel = (e == 0) ? B0 : ((e == 1) ? B1 : ((e == 2) ? B2 : B3));
        int ci = Bsel + offw + rank;
        // interval index for own (e, v) — folded into scatter
        const float* Ts = &Ts_l[e * 32];
        int k = 0;
        #pragma unroll
        for (int st = 32; st >= 1; st >>= 1)
            if (k + st <= 32 && Ts[k + st - 1] <= v) k += st;
        kv[ci] = make_int2((e * 33 + k) * 128, __float_as_int(v));
        float4 r4;
        r4.x = x[xb + 512 + 4 * tid + 0] * maskf;
        r4.y = x[xb + 512 + 4 * tid + 1] * maskf;
        r4.z = x[xb + 512 + 4 * tid + 2] * maskf;
        r4.w = x[xb + 512 + 4 * tid + 3] * maskf;
        Rm4[ci] = r4;
    }
    __syncthreads();

    // ---- T[e][c] = sum_a R_masked; fixed-trip masked loop (pads = 0) ----
    {
        int te = tid >> 6, tc = (tid >> 4) & 3, tk = tid & 15;
        int s0 = (te == 0) ? B0 : ((te == 1) ? B1 : ((te == 2) ? B2 : B3));
        int s1 = (te == 0) ? B1 : ((te == 1) ? B2 : ((te == 2) ? B3 : St4));
        float ts = 0.f;
        #pragma unroll
        for (int j = 0; j < 20; ++j) {
            int s = j * 16 + tk;
            float val = ((const float*)&Rm4[s])[tc];
            ts += (s >= s0 && s < s1) ? val : 0.f;
        }
        Tpart[te][tc][tk] = ts;
    }
    __syncthreads();
    if (tid < 16) {
        float t = 0.f;
        #pragma unroll
        for (int k = 0; k < 16; ++k) t += Tpart[tid >> 2][tid & 3][k];
        T16[tid] = t;         // consumed in P phase (after Spart barrier)
    }

    // ---- barrier-free S accumulation: wave w owns strips {t*64 + w*16} ----
    float Se[4][4];           // [expert][c] accumulators, static indexed
    #pragma unroll
    for (int i = 0; i < 4; ++i)
        #pragma unroll
        for (int j = 0; j < 4; ++j) Se[i][j] = 0.f;

    #pragma unroll
    for (int t = 0; t < 5; ++t) {
        const int base = t * 64 + w * 16;
        if (base >= St4) continue;           // wave-uniform: all-pad strip
        int2   kvu = kv[base + (lane & 15)];     // lanes replicate 16 slots
        float4 r4u = Rm4[base + (lane & 15)];

        float2 ac16[16];
        #pragma unroll
        for (int u = 0; u < 16; ++u) {
            int s_k = rli(kvu.x, u);             // SGPR: coalesced saddr load
            ac16[u] = *(const float2*)&ACg[s_k + 2 * lane];
        }
        #pragma unroll
        for (int g = 0; g < 4; ++g) {            // 4-aligned, expert-pure groups
            float t0 = 0.f, t1 = 0.f, t2 = 0.f, t3 = 0.f;
            #pragma unroll
            for (int u4 = 0; u4 < 4; ++u4) {
                const int u = g * 4 + u4;
                float s_v = rlf(__int_as_float(kvu.y), u);
                float h = fmaxf(fmaf(s_v, ac16[u].x, ac16[u].y), 0.f);
                t0 = fmaf(h, rlf(r4u.x, u), t0);
                t1 = fmaf(h, rlf(r4u.y, u), t1);
                t2 = fmaf(h, rlf(r4u.z, u), t2);
                t3 = fmaf(h, rlf(r4u.w, u), t3);
            }
            const int gb = base + g * 4;
            int eg = (gb >= B1) + (gb >= B2) + (gb >= B3);
            eg = __builtin_amdgcn_readfirstlane(eg);   // wave-uniform branch
            if (eg == 0) {
                Se[0][0] += t0; Se[0][1] += t1; Se[0][2] += t2; Se[0][3] += t3;
            } else if (eg == 1) {
                Se[1][0] += t0; Se[1][1] += t1; Se[1][2] += t2; Se[1][3] += t3;
            } else if (eg == 2) {
                Se[2][0] += t0; Se[2][1] += t1; Se[2][2] += t2; Se[2][3] += t3;
            } else {
                Se[3][0] += t0; Se[3][1] += t1; Se[3][2] += t2; Se[3][3] += t3;
            }
        }
    }
    #pragma unroll
    for (int ee = 0; ee < 4; ++ee) {
        float4 s4; s4.x = Se[ee][0]; s4.y = Se[ee][1];
                   s4.z = Se[ee][2]; s4.w = Se[ee][3];
        *(float4*)&Spart[w][ee][lane][0] = s4;
    }
    __syncthreads();

    // ---- reduce Spart over waves: thread (e,i) ----
    {
        const int e_ = tid >> 6, i_ = tid & 63;
        float4 s0 = *(const float4*)&Spart[0][e_][i_][0];
        float4 s1 = *(const float4*)&Spart[1][e_][i_][0];
        float4 s2 = *(const float4*)&Spart[2][e_][i_][0];
        float4 s3 = *(const float4*)&Spart[3][e_][i_][0];
        float4 r; r.x = (s0.x + s1.x) + (s2.x + s3.x);
                  r.y = (s0.y + s1.y) + (s2.y + s3.y);
                  r.z = (s0.z + s1.z) + (s2.z + s3.z);
                  r.w = (s0.w + s1.w) + (s2.w + s3.w);
        *(float4*)&Sred[e_][i_][0] = r;
    }
    __syncthreads();   // Spart dead past here -> Pp/Pr5 reuse the bytes

    // ---- P partials: wave w = expert; lane m-pair {lane, lane+64} ----
    {
        float a0 = 0.f, a1 = 0.f, a2 = 0.f, a3 = 0.f;   // m = lane
        float b0 = 0.f, b1_ = 0.f, b2_ = 0.f, b3_ = 0.f; // m = lane+64
        const float* W3e = W3 + w * 8192;
        #pragma unroll 8
        for (int i = 0; i < 64; ++i) {
            const float4 s4 = *(const float4*)&Sred[w][i][0];  // broadcast
            float wa = W3e[i * 128 + lane];
            float wb = W3e[i * 128 + 64 + lane];
            a0 = fmaf(wa, s4.x, a0); a1 = fmaf(wa, s4.y, a1);
            a2 = fmaf(wa, s4.z, a2); a3 = fmaf(wa, s4.w, a3);
            b0 = fmaf(wb, s4.x, b0); b1_ = fmaf(wb, s4.y, b1_);
            b2_ = fmaf(wb, s4.z, b2_); b3_ = fmaf(wb, s4.w, b3_);
        }
        const float4 t4 = *(const float4*)&T16[w * 4];
        float bya = b3[w * 128 + lane];
        float byb = b3[w * 128 + 64 + lane];
        a0 = fmaf(bya, t4.x, a0); a1 = fmaf(bya, t4.y, a1);
        a2 = fmaf(bya, t4.z, a2); a3 = fmaf(bya, t4.w, a3);
        b0 = fmaf(byb, t4.x, b0); b1_ = fmaf(byb, t4.y, b1_);
        b2_ = fmaf(byb, t4.z, b2_); b3_ = fmaf(byb, t4.w, b3_);
        float4 pa; pa.x = a0; pa.y = a1; pa.z = a2; pa.w = a3;
        float4 pb; pb.x = b0; pb.y = b1_; pb.z = b2_; pb.w = b3_;
        *(float4*)&Pp[w][lane][0]      = pa;
        *(float4*)&Pp[w][lane + 64][0] = pb;
    }
    __syncthreads();

    // ---- reduce Pp over experts -> Pr5 (disjoint region within uni) ----
    {
        const int m = tid >> 1, cp = tid & 1;
        float2 p0 = *(const float2*)&Pp[0][m][2 * cp];
        float2 p1 = *(const float2*)&Pp[1][m][2 * cp];
        float2 p2 = *(const float2*)&Pp[2][m][2 * cp];
        float2 p3 = *(const float2*)&Pp[3][m][2 * cp];
        Pr5[m * 5 + 2 * cp]     = (p0.x + p1.x) + (p2.x + p3.x);
        Pr5[m * 5 + 2 * cp + 1] = (p0.y + p1.y) + (p2.y + p3.y);
    }
    __syncthreads();

    // ---- D[m][n] = sum_c P[m][c] P[n][c]; 8 consecutive outputs/thread ----
    {
        const int m   = tid >> 1;
        const int nb8 = (tid & 1) << 3;
        float pm0 = Pr5[m * 5 + 0], pm1 = Pr5[m * 5 + 1];
        float pm2 = Pr5[m * 5 + 2], pm3 = Pr5[m * 5 + 3];
        float o8[8];
        #pragma unroll
        for (int r = 0; r < 8; ++r) {
            int n = nb8 + r;
            float d = pm0 * Pr5[n * 5 + 0];
            d = fmaf(pm1, Pr5[n * 5 + 1], d);
            d = fmaf(pm2, Pr5[n * 5 + 2], d);
            d = fmaf(pm3, Pr5[n * 5 + 3], d);
            o8[r] = d;
        }
        float* outb = out + (long)b * 2048 + tid * 8;
        float4 s0; s0.x = o8[0]; s0.y = o8[1]; s0.z = o8[2]; s0.w = o8[3];
        float4 s1; s1.x = o8[4]; s1.y = o8[5]; s1.z = o8[6]; s1.w = o8[7];
        *(float4*)&outb[0] = s0;
        *(float4*)&outb[4] = s1;
    }
}

extern "C" void kernel_launch(void* const* d_in, const int* in_sizes, int n_in,
                              void* d_out, int out_size, void* d_ws, size_t ws_size,
                              hipStream_t stream)
{
    const float* x  = (const float*)d_in[0];
    const float* W1 = (const float*)d_in[1];
    const float* b1 = (const float*)d_in[2];
    const float* W2 = (const float*)d_in[3];
    const float* b2 = (const float*)d_in[4];
    const float* W3 = (const float*)d_in[5];
    const float* b3 = (const float*)d_in[6];
    float* out = (float*)d_out;
    float* ws  = (float*)d_ws;       // needs 68096 bytes

    be_prep<<<132, 64, 0, stream>>>(W1, b1, W2, b2, ws);
    be_kernel<<<1024, NTHR, 0, stream>>>(x, W3, b3, ws, out);
}